// Round 17
// baseline (182.195 us; speedup 1.0000x reference)
//
#include <hip/hip_runtime.h>
#include <hip/hip_bf16.h>
#include <cstdint>

typedef __bf16 bf16;
typedef __attribute__((ext_vector_type(8))) __bf16 bf16x8;
typedef __attribute__((ext_vector_type(4))) __bf16 bf16x4;
typedef __attribute__((ext_vector_type(4))) float f32x4;

#define MFMA16 __builtin_amdgcn_mfma_f32_16x16x32_bf16
#define MASKV (-1e30f)

static constexpr int Lq  = 2048;
static constexpr int BKt = 64;

__device__ __forceinline__ void async_load16(const void* g, void* l) {
  __builtin_amdgcn_global_load_lds(
      (__attribute__((address_space(1))) void*)g,
      (__attribute__((address_space(3))) void*)l, 16, 0, 0);
}

__device__ __forceinline__ unsigned pack2bf(float lo, float hi) {
  bf16 a = (bf16)lo, c = (bf16)hi;
  unsigned short ua, uc;
  __builtin_memcpy(&ua, &a, 2);
  __builtin_memcpy(&uc, &c, 2);
  return ((unsigned)uc << 16) | ua;
}

// ---------------------------------------------------------------------------
// fp32 -> bf16 conversion of all inputs + zero s_buf (merged)
// ---------------------------------------------------------------------------
__global__ void convert_all(const float* __restrict__ q, const float* __restrict__ k,
                            const float* __restrict__ v, const float* __restrict__ wq,
                            const float* __restrict__ wk, const float* __restrict__ wv,
                            const float* __restrict__ fc, const float* __restrict__ E,
                            bf16* q_bf, bf16* k_bf, bf16* v_bf, bf16* wq_bf,
                            bf16* wk_bf, bf16* wv_bf, bf16* fc_bf, bf16* E_bf,
                            float* s_buf)
{
  int i = blockIdx.x * blockDim.x + threadIdx.x;   // vec4 index
  const float* src; bf16* dst; int rel;
  if      (i < 524288)  { src = q;  dst = q_bf;  rel = i; }
  else if (i < 1048576) { src = k;  dst = k_bf;  rel = i - 524288; }
  else if (i < 1572864) { src = v;  dst = v_bf;  rel = i - 1048576; }
  else if (i < 1638400) { src = wq; dst = wq_bf; rel = i - 1572864; }
  else if (i < 1703936) { src = wk; dst = wk_bf; rel = i - 1638400; }
  else if (i < 1769472) { src = wv; dst = wv_bf; rel = i - 1703936; }
  else if (i < 1835008) { src = fc; dst = fc_bf; rel = i - 1769472; }
  else if (i < 1867776) { src = E;  dst = E_bf;  rel = i - 1835008; }
  else if (i < 1875968) {            // zero s_buf (8192 float4)
    ((float4*)s_buf)[i - 1867776] = make_float4(0.f, 0.f, 0.f, 0.f);
    return;
  }
  else return;
  float4 x = *(const float4*)(src + (size_t)rel * 4);
  bf16x4 o;
  o[0] = (bf16)x.x; o[1] = (bf16)x.y; o[2] = (bf16)x.z; o[3] = (bf16)x.w;
  *(bf16x4*)(dst + (size_t)rel * 4) = o;
}

// ---------------------------------------------------------------------------
// 128x128-tile bf16 GEMM core. MODE 0/2/3 as before.
// ---------------------------------------------------------------------------
template<int MODE>
__device__ __forceinline__
void gemm512_core(const bf16* __restrict__ A, const bf16* __restrict__ Bm,
                  const float* __restrict__ bias, void* __restrict__ Cv,
                  int tm, int tn, char* lA, char* lB)
{
  const int tid = threadIdx.x, lane = tid & 63, wv = tid >> 6;
  const int wr = wv >> 1, wc = wv & 1;

  f32x4 acc[4][4];
#pragma unroll
  for (int m = 0; m < 4; ++m)
#pragma unroll
    for (int n = 0; n < 4; ++n) acc[m][n] = (f32x4){0.f, 0.f, 0.f, 0.f};

  for (int k0 = 0; k0 < 512; k0 += 64) {
    __syncthreads();
#pragma unroll
    for (int it = 0; it < 4; ++it) {
      int slot = it * 256 + wv * 64 + lane;
      int row = slot >> 3, c = slot & 7;
      int gk = k0 + ((c ^ (row & 7)) * 8);
      async_load16(A  + (size_t)(tm * 128 + row) * 512 + gk, lA + (it * 256 + wv * 64) * 16);
      async_load16(Bm + (size_t)(tn * 128 + row) * 512 + gk, lB + (it * 256 + wv * 64) * 16);
    }
    __syncthreads();
#pragma unroll
    for (int kc = 0; kc < 2; ++kc) {
      bf16x8 af[4], bfr[4];
#pragma unroll
      for (int m = 0; m < 4; ++m) {
        int row = wr * 64 + m * 16 + (lane & 15);
        int ch = ((lane >> 4) + kc * 4) ^ (row & 7);
        af[m] = *(const bf16x8*)(lA + row * 128 + ch * 16);
      }
#pragma unroll
      for (int n = 0; n < 4; ++n) {
        int row = wc * 64 + n * 16 + (lane & 15);
        int ch = ((lane >> 4) + kc * 4) ^ (row & 7);
        bfr[n] = *(const bf16x8*)(lB + row * 128 + ch * 16);
      }
#pragma unroll
      for (int m = 0; m < 4; ++m)
#pragma unroll
        for (int n = 0; n < 4; ++n)
          acc[m][n] = MFMA16(af[m], bfr[n], acc[m][n], 0, 0, 0);
    }
  }

#pragma unroll
  for (int m = 0; m < 4; ++m)
#pragma unroll
    for (int n = 0; n < 4; ++n)
#pragma unroll
      for (int r = 0; r < 4; ++r) {
        int gi = tm * 128 + wr * 64 + m * 16 + 4 * (lane >> 4) + r;
        int gj = tn * 128 + wc * 64 + n * 16 + (lane & 15);
        float vv = acc[m][n][r] + ((MODE == 2) ? bias[gi] : bias[gj]);
        if (MODE == 3) {
          ((float*)Cv)[(size_t)gi * 512 + gj] = vv;
        } else if (MODE == 2) {
          int h = gi >> 6, dh = gi & 63, b = gj >> 11, l = gj & 2047;
          ((bf16*)Cv)[((size_t)((b * 8 + h) * 64 + dh)) * 2048 + l] = (bf16)vv;
        } else {
          int b = gi >> 11, l = gi & 2047, h = gj >> 6, dh = gj & 63;
          ((bf16*)Cv)[((size_t)((b * 8 + h) * 2048 + l)) * 64 + dh] = (bf16)vv;
        }
      }
}

__global__ __launch_bounds__(256, 2)
void gemm_qkv(const bf16* __restrict__ q_bf, const bf16* __restrict__ k_bf,
              const bf16* __restrict__ v_bf, const bf16* __restrict__ wq_bf,
              const bf16* __restrict__ wk_bf, const bf16* __restrict__ wv_bf,
              const float* __restrict__ wq_b, const float* __restrict__ wk_b,
              const float* __restrict__ wv_b,
              bf16* __restrict__ qh, bf16* __restrict__ kh, bf16* __restrict__ vt)
{
  __shared__ __align__(16) char lA[16384];
  __shared__ __align__(16) char lB[16384];
  const int z = blockIdx.z;
  if (z == 0)      gemm512_core<0>(q_bf, wq_bf, wq_b, qh, blockIdx.x, blockIdx.y, lA, lB);
  else if (z == 1) gemm512_core<0>(k_bf, wk_bf, wk_b, kh, blockIdx.x, blockIdx.y, lA, lB);
  else             gemm512_core<2>(wv_bf, v_bf, wv_b, vt, blockIdx.y, blockIdx.x, lA, lB);
}

__global__ __launch_bounds__(256, 2)
void gemm_fc(const bf16* __restrict__ A, const bf16* __restrict__ Bm,
             const float* __restrict__ bias, float* __restrict__ Cv)
{
  __shared__ __align__(16) char lA[16384];
  __shared__ __align__(16) char lB[16384];
  gemm512_core<3>(A, Bm, bias, Cv, blockIdx.x, blockIdx.y, lA, lB);
}

// ---------------------------------------------------------------------------
// Attention helpers
// ---------------------------------------------------------------------------
__device__ __forceinline__ void stage_k(const bf16* __restrict__ kb, int j0,
                                        char* dst, int tid) {
#pragma unroll
  for (int it = 0; it < 2; ++it) {
    int slot = it * 256 + tid;
    int row = slot >> 3, c = slot & 7;
    async_load16(kb + (size_t)(j0 + row) * 64 + ((c ^ (row & 7)) * 8), dst + slot * 16);
  }
}
__device__ __forceinline__ void stage_v(const bf16* __restrict__ vb, int j0,
                                        char* dst, int tid) {
#pragma unroll
  for (int it = 0; it < 2; ++it) {
    int slot = it * 256 + tid;
    int row = slot >> 3, c = slot & 7;
    async_load16(vb + (size_t)row * Lq + j0 + ((c ^ (row & 7)) * 8), dst + slot * 16);
  }
}
// Stage one 64-row aligned E block into ring slot (block & 3). Block b holds
// absolute E rows [64b, 64b+63] (clamped); swizzle key = row & 7 = abs & 7.
__device__ __forceinline__ void stage_e_block(const bf16* __restrict__ Ebf, int block,
                                              char* e_base, int tid) {
  char* dst = e_base + (size_t)(block & 3) * 8192;
#pragma unroll
  for (int it = 0; it < 2; ++it) {
    int slot = it * 256 + tid;           // 0..511
    int row = slot >> 3, c = slot & 7;   // row 0..63
    int a = block * 64 + row;
    int re = a < 0 ? 0 : (a > 2047 ? 2047 : a);
    async_load16(Ebf + (size_t)re * 64 + ((c ^ (row & 7)) * 8), dst + slot * 16);
  }
}

// Logits for one 16q x 64k tile: acc_s = (QK + Srel)/8, masked -> MASKV.
// E fragments from the 4-slot LDS ring (conflict-free b128 reads);
// T diagonal gather via packed bf16x2 single-shuffle.
__device__ __forceinline__ void attn_logits_sh(
    int i0, int j0, int wvx, int lane,
    const bf16x8 qf0, const bf16x8 qf1,
    const char* le, const char* lk, f32x4 acc_s[4])
{
  const int g = lane >> 4, b = lane & 15;
  const int rebase = 2110 - i0 + j0;
  f32x4 acc_t[5];
#pragma unroll
  for (int cf = 0; cf < 5; ++cf) {
    int t = wvx * 16 + cf * 16 + b;            // 0..127
    int re = rebase - t;
    re = re < 0 ? 0 : re;                      // clamp lands in a staged block
    int c0 = g ^ (re & 7), c1 = (g + 4) ^ (re & 7);
    const char* ep = le + ((re >> 6) & 3) * 8192 + (re & 63) * 128;
    f32x4 a = (f32x4){0.f, 0.f, 0.f, 0.f};
    a = MFMA16(qf0, *(const bf16x8*)(ep + c0 * 16), a, 0, 0, 0);
    a = MFMA16(qf1, *(const bf16x8*)(ep + c1 * 16), a, 0, 0, 0);
    acc_t[cf] = a;
  }
#pragma unroll
  for (int cf = 0; cf < 4; ++cf) {
    int key = cf * 16 + b;
    int c0 = g ^ (key & 7);
    int c1 = (g + 4) ^ (key & 7);
    f32x4 a = (f32x4){0.f, 0.f, 0.f, 0.f};
    a = MFMA16(qf0, *(const bf16x8*)(lk + key * 128 + c0 * 16), a, 0, 0, 0);
    a = MFMA16(qf1, *(const bf16x8*)(lk + key * 128 + c1 * 16), a, 0, 0, 0);
    acc_s[cf] = a;
  }
  // pack T pairs (lo = acc_t[c], hi = acc_t[c+1]) as bf16x2 -> one shuffle
  unsigned pr[4][4];
#pragma unroll
  for (int c = 0; c < 4; ++c)
#pragma unroll
    for (int r = 0; r < 4; ++r)
      pr[c][r] = pack2bf(acc_t[c][r], acc_t[c + 1][r]);

#pragma unroll
  for (int r = 0; r < 4; ++r) {
    const int qw  = 4 * g + r;
    const int sl  = (lane & 48) | ((63 + qw - b) & 15);
    const bool hi = qw > b;
#pragma unroll
    for (int cf = 0; cf < 4; ++cf) {
      unsigned u = __shfl(pr[3 - cf][r], sl);
      float t = hi ? __uint_as_float(u & 0xffff0000u)
                   : __uint_as_float(u << 16);
      float vv = (acc_s[cf][r] + t) * 0.125f;
      if (j0 + cf * 16 + b > i0 + wvx * 16 + qw) vv = MASKV;
      acc_s[cf][r] = vv;
    }
  }
}

// ---------------------------------------------------------------------------
// PRODUCE (single logits pass): grid 4096 = 8 xcd * 2 bh * 256 u.
// u -> qt = 31-(u>>3) (heavy chunks dispatch FIRST), f = u&7.
// K/V dbuf + E 4-slot ring (window shifts 64 rows/step -> prefetch only the
// ONE new 64-row block per step). Loop body has zero global loads.
// ---------------------------------------------------------------------------
__global__ __launch_bounds__(256, 2)
void produce(const bf16* __restrict__ qh, const bf16* __restrict__ kh,
             const bf16* __restrict__ vt, const bf16* __restrict__ Ebf,
             bf16* __restrict__ P_scr, float* __restrict__ O_slots,
             float* __restrict__ s_buf, float* __restrict__ attn_out)
{
  __shared__ __align__(16) char lds_k[2][64 * 128];   // 16 KB
  __shared__ __align__(16) char lds_v[2][64 * 128];   // 16 KB
  __shared__ __align__(16) char lds_e[4 * 64 * 128];  // 32 KB (4-slot ring)
  __shared__ __align__(16) char lds_p[4][16 * 64 * 2];// 8 KB

  const int tid = threadIdx.x, lane = tid & 63, wvx = tid >> 6;
  const int n    = blockIdx.x;
  const int xcd  = n & 7;
  const int r0   = n >> 3;               // 0..511
  const int bh   = 2 * xcd + (r0 & 1);
  const int u    = r0 >> 1;              // 0..255
  const int f    = u & 7;                // chunk index 0..7
  const int qt   = 31 - (u >> 3);        // heavy qt first in dispatch order
  const int nc   = (qt >> 2) + 1;        // # compute chunks for this qt
  if (f >= nc) return;                   // non-compute slot
  const int i0   = qt * 64;
  const int jbeg = f * 4;
  const int jend = (jbeg + 4 < qt + 1) ? jbeg + 4 : qt + 1;

  const bf16* qb = qh + (size_t)bh * Lq * 64;
  const bf16* kb = kh + (size_t)bh * Lq * 64;
  const bf16* vb = vt + (size_t)bh * 64 * Lq;
  float* attn_b = attn_out + (size_t)bh * Lq * Lq;
  bf16* P_b = P_scr + (size_t)bh * Lq * Lq;
  bf16* pst = (bf16*)lds_p[wvx];

  const int qrow = i0 + wvx * 16 + (lane & 15);
  const bf16x8 qf0 = *(const bf16x8*)(qb + (size_t)qrow * 64 + (lane >> 4) * 8);
  const bf16x8 qf1 = *(const bf16x8*)(qb + (size_t)qrow * 64 + 32 + (lane >> 4) * 8);

  f32x4 acc_s[4];
  f32x4 acc_o[4];
  float s_acc[4] = {0.f, 0.f, 0.f, 0.f};
#pragma unroll
  for (int nn = 0; nn < 4; ++nn) acc_o[nn] = (f32x4){0.f, 0.f, 0.f, 0.f};

  // prologue: stage first K/V tile + the 3 E blocks of the first window
  const int m0 = (2110 - i0 + jbeg * BKt) >> 6;
  stage_k(kb, jbeg * BKt, lds_k[0], tid);
  stage_v(vb, jbeg * BKt, lds_v[0], tid);
  stage_e_block(Ebf, m0 - 2, lds_e, tid);
  stage_e_block(Ebf, m0 - 1, lds_e, tid);
  stage_e_block(Ebf, m0,     lds_e, tid);
  asm volatile("s_waitcnt vmcnt(0)" ::: "memory");
  __builtin_amdgcn_s_barrier();

  int lt = 0;
  for (int jt = jbeg; jt < jend; ++jt) {
    const int j0 = jt * BKt;
    const bool pre = (jt + 1 < jend);
    // issue next-tile staging first (loop body has no other global loads)
    if (pre) {
      stage_k(kb, j0 + BKt, lds_k[lt ^ 1], tid);
      stage_v(vb, j0 + BKt, lds_v[lt ^ 1], tid);
      stage_e_block(Ebf, m0 + 1 + (jt - jbeg), lds_e, tid);  // one new block
    }
    attn_logits_sh(i0, j0, wvx, lane, qf0, qf1, lds_e, lds_k[lt], acc_s);
    // unnormalized exp -> sum + swizzled P strip (bf16)
#pragma unroll
    for (int cf = 0; cf < 4; ++cf) {
      int kl = cf * 16 + (lane & 15);
      int chs = kl >> 3;
#pragma unroll
      for (int r = 0; r < 4; ++r) {
        int qw = 4 * (lane >> 4) + r;
        float p = __expf(acc_s[cf][r]);
        s_acc[r] += p;
        pst[qw * 64 + ((chs ^ (qw & 7)) * 8) + (kl & 7)] = (bf16)p;
      }
    }
    asm volatile("s_waitcnt lgkmcnt(0)" ::: "memory");
    __builtin_amdgcn_sched_barrier(0);
    // P scratch write (bf16): 128B-contiguous per 8-lane group
#pragma unroll
    for (int it = 0; it < 2; ++it) {
      int qw = it * 8 + (lane >> 3);
      int c = lane & 7;
      bf16x8 pv = *(const bf16x8*)(pst + qw * 64 + ((c ^ (qw & 7)) * 8));
      *(bf16x8*)(P_b + (size_t)(i0 + wvx * 16 + qw) * Lq + j0 + c * 8) = pv;
    }
    // O += P.V (unnormalized)
    __builtin_amdgcn_s_setprio(1);
#pragma unroll
    for (int kc = 0; kc < 2; ++kc) {
      int qa = lane & 15;
      int cha = (kc * 4 + (lane >> 4)) ^ (qa & 7);
      bf16x8 pf = *(const bf16x8*)(pst + qa * 64 + cha * 8);
#pragma unroll
      for (int nn = 0; nn < 4; ++nn) {
        int dh = nn * 16 + (lane & 15);
        int chv = (kc * 4 + (lane >> 4)) ^ (dh & 7);
        bf16x8 vf = *(const bf16x8*)(lds_v[lt] + dh * 128 + chv * 16);
        acc_o[nn] = MFMA16(pf, vf, acc_o[nn], 0, 0, 0);
      }
    }
    __builtin_amdgcn_s_setprio(0);
    if (pre) {
      // counted wait: 6 stage loads must land (2 newest P-stores may linger)
      asm volatile("s_waitcnt vmcnt(2)" ::: "memory");
      __builtin_amdgcn_s_barrier();
      lt ^= 1;
    }
  }

  // O partial -> slot (fp32, unnormalized)
  float* oslot = O_slots + (size_t)(((bh * 32 + qt) * 8 + f)) * 4096;
#pragma unroll
  for (int nn = 0; nn < 4; ++nn)
#pragma unroll
    for (int r = 0; r < 4; ++r) {
      int row = wvx * 16 + 4 * (lane >> 4) + r;
      oslot[row * 64 + nn * 16 + (lane & 15)] = acc_o[nn][r];
    }

  // row-sum atomics
#pragma unroll
  for (int r = 0; r < 4; ++r) {
    float s = s_acc[r];
    for (int d = 1; d < 16; d <<= 1) s += __shfl_xor(s, d);
    if ((lane & 15) == 0)
      atomicAdd(&s_buf[bh * Lq + i0 + wvx * 16 + 4 * (lane >> 4) + r], s);
  }

  // zero-fill this chunk's share of the masked upper tiles (fire-and-forget)
  for (int jz = qt + 1 + f; jz < 32; jz += nc) {
    const int j0 = jz * BKt;
#pragma unroll
    for (int kk = 0; kk < 4; ++kk) {
      int idx = kk * 256 + tid;          // 0..1023 float4 slots in 64x64 tile
      int row = idx >> 4, c4 = idx & 15;
      float* p = attn_b + (size_t)(i0 + row) * Lq + j0 + c4 * 4;
      *(float4*)p = make_float4(0.f, 0.f, 0.f, 0.f);
    }
  }
}

// ---------------------------------------------------------------------------
// FINISH: streaming normalize, fully coalesced. One wave per row (4/block).
// Covers only cols [0, (i&~63)+64) -- masked tiles already zeroed by produce;
// in-tile masked entries are exact 0 in P so no per-element masking needed.
// ---------------------------------------------------------------------------
__global__ __launch_bounds__(256, 8)
void finish(const bf16* __restrict__ P_scr, const float* __restrict__ s_buf,
            float* __restrict__ attn_out)
{
  const int lane = threadIdx.x & 63, wvx = threadIdx.x >> 6;
  const int row = blockIdx.x * 4 + wvx;          // 0..32767 = bh*2048 + i
  const int i   = row & 2047;
  const int ncols = (i & ~63) + 64;
  const float inv = 1.f / s_buf[row];
  const bf16* src = P_scr + (size_t)row * Lq;
  float* dst = attn_out + (size_t)row * Lq;
  for (int c = lane * 4; c < ncols; c += 256) {
    bf16x4 pv = *(const bf16x4*)(src + c);
    float4 fo;
    fo.x = (float)pv[0] * inv;
    fo.y = (float)pv[1] * inv;
    fo.z = (float)pv[2] * inv;
    fo.w = (float)pv[3] * inv;
    *(float4*)(dst + c) = fo;
  }
}

// ---------------------------------------------------------------------------
// Combine O slots -> oh (bf16), scaling by inv_s. Grid 512 = [bh][qt].
// ---------------------------------------------------------------------------
__global__ void combine_o(const float* __restrict__ O_slots,
                          const float* __restrict__ s_buf, bf16* __restrict__ oh)
{
  const int sid = blockIdx.x;            // 0..511
  const int bh = sid >> 5, qt = sid & 31;
  const int nch = (qt >> 2) + 1;
  const float* base = O_slots + (size_t)(bh * 32 + qt) * 8 * 4096;
  const int b = bh >> 3, h = bh & 7;
  for (int e4 = threadIdx.x; e4 < 1024; e4 += 256) {
    float4 s = make_float4(0.f, 0.f, 0.f, 0.f);
    for (int ff = 0; ff < nch; ++ff) {
      float4 x = *(const float4*)(base + ff * 4096 + e4 * 4);
      s.x += x.x; s.y += x.y; s.z += x.z; s.w += x.w;
    }
    int row = e4 >> 4;                   // 0..63 within strip
    int col = (e4 & 15) * 4;
    int ig = qt * 64 + row;
    float inv = 1.f / s_buf[bh * Lq + ig];
    bf16x4 o;
    o[0] = (bf16)(s.x * inv); o[1] = (bf16)(s.y * inv);
    o[2] = (bf16)(s.z * inv); o[3] = (bf16)(s.w * inv);
    *(bf16x4*)(oh + (size_t)(b * 2048 + ig) * 512 + h * 64 + col) = o;
  }
}

// ---------------------------------------------------------------------------
extern "C" void kernel_launch(void* const* d_in, const int* in_sizes, int n_in,
                              void* d_out, int out_size, void* d_ws, size_t ws_size,
                              hipStream_t stream) {
  const float* q    = (const float*)d_in[0];
  const float* k    = (const float*)d_in[1];
  const float* v    = (const float*)d_in[2];
  const float* wq   = (const float*)d_in[3];
  const float* wq_b = (const float*)d_in[4];
  const float* wk   = (const float*)d_in[5];
  const float* wk_b = (const float*)d_in[6];
  const float* wv   = (const float*)d_in[7];
  const float* wv_b = (const float*)d_in[8];
  const float* fc   = (const float*)d_in[9];
  const float* fc_b = (const float*)d_in[10];
  const float* E    = (const float*)d_in[11];

  if (ws_size < 233177088) return;  // layout below (~222 MiB); observed ws ~1.1 GB
  char* ws = (char*)d_ws;
  bf16*  q_bf    = (bf16*)(ws);
  bf16*  k_bf    = (bf16*)(ws + 4194304);
  bf16*  v_bf    = (bf16*)(ws + 8388608);
  bf16*  wq_bf   = (bf16*)(ws + 12582912);
  bf16*  wk_bf   = (bf16*)(ws + 13107200);
  bf16*  wv_bf   = (bf16*)(ws + 13631488);
  bf16*  fc_bf   = (bf16*)(ws + 14155776);
  bf16*  E_bf    = (bf16*)(ws + 14680064);
  float* s_buf   = (float*)(ws + 14942208);
  bf16*  qh_bf   = (bf16*)(ws + 15073280);
  bf16*  kh_bf   = (bf16*)(ws + 19267584);
  bf16*  vt_bf   = (bf16*)(ws + 23461888);
  bf16*  oh_bf   = (bf16*)(ws + 27656192);
  float* O_slots = (float*)(ws + 31850496);   // 64 MiB
  bf16*  P_scr   = (bf16*)(ws + 98959360);    // 128 MiB

  float* out_f  = (float*)d_out;
  float* attn_f = out_f + 2097152;

  convert_all<<<7328, 256, 0, stream>>>(q, k, v, wq, wk, wv, fc, E,
      q_bf, k_bf, v_bf, wq_bf, wk_bf, wv_bf, fc_bf, E_bf, s_buf);
  gemm_qkv<<<dim3(32, 4, 3), 256, 0, stream>>>(q_bf, k_bf, v_bf,
      wq_bf, wk_bf, wv_bf, wq_b, wk_b, wv_b, qh_bf, kh_bf, vt_bf);
  produce<<<4096, 256, 0, stream>>>(qh_bf, kh_bf, vt_bf, E_bf,
                                    P_scr, O_slots, s_buf, attn_f);
  finish<<<8192, 256, 0, stream>>>(P_scr, s_buf, attn_f);
  combine_o<<<512, 256, 0, stream>>>(O_slots, s_buf, oh_bf);
  gemm_fc<<<dim3(32, 4), 256, 0, stream>>>(oh_bf, fc_bf, fc_b, out_f);
}

// Round 18
// 179.434 us; speedup vs baseline: 1.0154x; 1.0154x over previous
//
#include <hip/hip_runtime.h>
#include <hip/hip_bf16.h>
#include <cstdint>

typedef __bf16 bf16;
typedef __attribute__((ext_vector_type(8))) __bf16 bf16x8;
typedef __attribute__((ext_vector_type(4))) __bf16 bf16x4;
typedef __attribute__((ext_vector_type(4))) float f32x4;

#define MFMA16 __builtin_amdgcn_mfma_f32_16x16x32_bf16
#define MASKV (-1e30f)

static constexpr int Lq  = 2048;
static constexpr int BKt = 64;

__device__ __forceinline__ void async_load16(const void* g, void* l) {
  __builtin_amdgcn_global_load_lds(
      (__attribute__((address_space(1))) void*)g,
      (__attribute__((address_space(3))) void*)l, 16, 0, 0);
}

__device__ __forceinline__ unsigned pack2bf(float lo, float hi) {
  bf16 a = (bf16)lo, c = (bf16)hi;
  unsigned short ua, uc;
  __builtin_memcpy(&ua, &a, 2);
  __builtin_memcpy(&uc, &c, 2);
  return ((unsigned)uc << 16) | ua;
}

// ---------------------------------------------------------------------------
// fp32 -> bf16 conversion of all inputs + zero s_buf (merged)
// ---------------------------------------------------------------------------
__global__ void convert_all(const float* __restrict__ q, const float* __restrict__ k,
                            const float* __restrict__ v, const float* __restrict__ wq,
                            const float* __restrict__ wk, const float* __restrict__ wv,
                            const float* __restrict__ fc, const float* __restrict__ E,
                            bf16* q_bf, bf16* k_bf, bf16* v_bf, bf16* wq_bf,
                            bf16* wk_bf, bf16* wv_bf, bf16* fc_bf, bf16* E_bf,
                            float* s_buf)
{
  int i = blockIdx.x * blockDim.x + threadIdx.x;   // vec4 index
  const float* src; bf16* dst; int rel;
  if      (i < 524288)  { src = q;  dst = q_bf;  rel = i; }
  else if (i < 1048576) { src = k;  dst = k_bf;  rel = i - 524288; }
  else if (i < 1572864) { src = v;  dst = v_bf;  rel = i - 1048576; }
  else if (i < 1638400) { src = wq; dst = wq_bf; rel = i - 1572864; }
  else if (i < 1703936) { src = wk; dst = wk_bf; rel = i - 1638400; }
  else if (i < 1769472) { src = wv; dst = wv_bf; rel = i - 1703936; }
  else if (i < 1835008) { src = fc; dst = fc_bf; rel = i - 1769472; }
  else if (i < 1867776) { src = E;  dst = E_bf;  rel = i - 1835008; }
  else if (i < 1875968) {            // zero s_buf (8192 float4)
    ((float4*)s_buf)[i - 1867776] = make_float4(0.f, 0.f, 0.f, 0.f);
    return;
  }
  else return;
  float4 x = *(const float4*)(src + (size_t)rel * 4);
  bf16x4 o;
  o[0] = (bf16)x.x; o[1] = (bf16)x.y; o[2] = (bf16)x.z; o[3] = (bf16)x.w;
  *(bf16x4*)(dst + (size_t)rel * 4) = o;
}

// ---------------------------------------------------------------------------
// 128x128-tile bf16 GEMM core. MODE 0/2/3 as before.
// ---------------------------------------------------------------------------
template<int MODE>
__device__ __forceinline__
void gemm512_core(const bf16* __restrict__ A, const bf16* __restrict__ Bm,
                  const float* __restrict__ bias, void* __restrict__ Cv,
                  int tm, int tn, char* lA, char* lB)
{
  const int tid = threadIdx.x, lane = tid & 63, wv = tid >> 6;
  const int wr = wv >> 1, wc = wv & 1;

  f32x4 acc[4][4];
#pragma unroll
  for (int m = 0; m < 4; ++m)
#pragma unroll
    for (int n = 0; n < 4; ++n) acc[m][n] = (f32x4){0.f, 0.f, 0.f, 0.f};

  for (int k0 = 0; k0 < 512; k0 += 64) {
    __syncthreads();
#pragma unroll
    for (int it = 0; it < 4; ++it) {
      int slot = it * 256 + wv * 64 + lane;
      int row = slot >> 3, c = slot & 7;
      int gk = k0 + ((c ^ (row & 7)) * 8);
      async_load16(A  + (size_t)(tm * 128 + row) * 512 + gk, lA + (it * 256 + wv * 64) * 16);
      async_load16(Bm + (size_t)(tn * 128 + row) * 512 + gk, lB + (it * 256 + wv * 64) * 16);
    }
    __syncthreads();
#pragma unroll
    for (int kc = 0; kc < 2; ++kc) {
      bf16x8 af[4], bfr[4];
#pragma unroll
      for (int m = 0; m < 4; ++m) {
        int row = wr * 64 + m * 16 + (lane & 15);
        int ch = ((lane >> 4) + kc * 4) ^ (row & 7);
        af[m] = *(const bf16x8*)(lA + row * 128 + ch * 16);
      }
#pragma unroll
      for (int n = 0; n < 4; ++n) {
        int row = wc * 64 + n * 16 + (lane & 15);
        int ch = ((lane >> 4) + kc * 4) ^ (row & 7);
        bfr[n] = *(const bf16x8*)(lB + row * 128 + ch * 16);
      }
#pragma unroll
      for (int m = 0; m < 4; ++m)
#pragma unroll
        for (int n = 0; n < 4; ++n)
          acc[m][n] = MFMA16(af[m], bfr[n], acc[m][n], 0, 0, 0);
    }
  }

#pragma unroll
  for (int m = 0; m < 4; ++m)
#pragma unroll
    for (int n = 0; n < 4; ++n)
#pragma unroll
      for (int r = 0; r < 4; ++r) {
        int gi = tm * 128 + wr * 64 + m * 16 + 4 * (lane >> 4) + r;
        int gj = tn * 128 + wc * 64 + n * 16 + (lane & 15);
        float vv = acc[m][n][r] + ((MODE == 2) ? bias[gi] : bias[gj]);
        if (MODE == 3) {
          ((float*)Cv)[(size_t)gi * 512 + gj] = vv;
        } else if (MODE == 2) {
          int h = gi >> 6, dh = gi & 63, b = gj >> 11, l = gj & 2047;
          ((bf16*)Cv)[((size_t)((b * 8 + h) * 64 + dh)) * 2048 + l] = (bf16)vv;
        } else {
          int b = gi >> 11, l = gi & 2047, h = gj >> 6, dh = gj & 63;
          ((bf16*)Cv)[((size_t)((b * 8 + h) * 2048 + l)) * 64 + dh] = (bf16)vv;
        }
      }
}

__global__ __launch_bounds__(256, 2)
void gemm_qkv(const bf16* __restrict__ q_bf, const bf16* __restrict__ k_bf,
              const bf16* __restrict__ v_bf, const bf16* __restrict__ wq_bf,
              const bf16* __restrict__ wk_bf, const bf16* __restrict__ wv_bf,
              const float* __restrict__ wq_b, const float* __restrict__ wk_b,
              const float* __restrict__ wv_b,
              bf16* __restrict__ qh, bf16* __restrict__ kh, bf16* __restrict__ vt)
{
  __shared__ __align__(16) char lA[16384];
  __shared__ __align__(16) char lB[16384];
  const int z = blockIdx.z;
  if (z == 0)      gemm512_core<0>(q_bf, wq_bf, wq_b, qh, blockIdx.x, blockIdx.y, lA, lB);
  else if (z == 1) gemm512_core<0>(k_bf, wk_bf, wk_b, kh, blockIdx.x, blockIdx.y, lA, lB);
  else             gemm512_core<2>(wv_bf, v_bf, wv_b, vt, blockIdx.y, blockIdx.x, lA, lB);
}

__global__ __launch_bounds__(256, 2)
void gemm_fc(const bf16* __restrict__ A, const bf16* __restrict__ Bm,
             const float* __restrict__ bias, float* __restrict__ Cv)
{
  __shared__ __align__(16) char lA[16384];
  __shared__ __align__(16) char lB[16384];
  gemm512_core<3>(A, Bm, bias, Cv, blockIdx.x, blockIdx.y, lA, lB);
}

// ---------------------------------------------------------------------------
// Attention helpers
// ---------------------------------------------------------------------------
__device__ __forceinline__ void stage_k(const bf16* __restrict__ kb, int j0,
                                        char* dst, int tid) {
#pragma unroll
  for (int it = 0; it < 2; ++it) {
    int slot = it * 256 + tid;
    int row = slot >> 3, c = slot & 7;
    async_load16(kb + (size_t)(j0 + row) * 64 + ((c ^ (row & 7)) * 8), dst + slot * 16);
  }
}
__device__ __forceinline__ void stage_v(const bf16* __restrict__ vb, int j0,
                                        char* dst, int tid) {
#pragma unroll
  for (int it = 0; it < 2; ++it) {
    int slot = it * 256 + tid;
    int row = slot >> 3, c = slot & 7;
    async_load16(vb + (size_t)row * Lq + j0 + ((c ^ (row & 7)) * 8), dst + slot * 16);
  }
}
// Stage the 128-row E window for tile j0 of row-block i0 (COALESCED -- this
// replaces 10 per-lane gathers/wave-step that each touched 64 cache lines).
// LDS row t holds E[clamp(rebase - t)] with the K-style XOR chunk swizzle.
// rebase = 2110 - i0 + j0; row_local for (wvx,cf,b) = wvx*16 + cf*16 + b.
__device__ __forceinline__ void stage_e(const bf16* __restrict__ Ebf, int rebase,
                                        char* dst, int tid) {
#pragma unroll
  for (int it = 0; it < 4; ++it) {
    int slot = it * 256 + tid;
    int t = slot >> 3, c = slot & 7;
    int re = rebase - t;
    re = re < 0 ? 0 : (re > 2047 ? 2047 : re);
    async_load16(Ebf + (size_t)re * 64 + ((c ^ (t & 7)) * 8), dst + slot * 16);
  }
}

// Logits for one 16q x 64k tile: acc_s = (QK + Srel)/8, masked -> MASKV.
// E fragments from the staged LDS window (conflict-free b128 reads);
// T diagonal gather via packed bf16x2 single-shuffle.
__device__ __forceinline__ void attn_logits_sh(
    int i0, int j0, int wvx, int lane,
    const bf16x8 qf0, const bf16x8 qf1,
    const char* le, const char* lk, f32x4 acc_s[4])
{
  const int g = lane >> 4, b = lane & 15;
  f32x4 acc_t[5];
#pragma unroll
  for (int cf = 0; cf < 5; ++cf) {
    int t = wvx * 16 + cf * 16 + b;            // row_local 0..127
    int c0 = g ^ (t & 7), c1 = (g + 4) ^ (t & 7);
    f32x4 a = (f32x4){0.f, 0.f, 0.f, 0.f};
    a = MFMA16(qf0, *(const bf16x8*)(le + t * 128 + c0 * 16), a, 0, 0, 0);
    a = MFMA16(qf1, *(const bf16x8*)(le + t * 128 + c1 * 16), a, 0, 0, 0);
    acc_t[cf] = a;
  }
#pragma unroll
  for (int cf = 0; cf < 4; ++cf) {
    int key = cf * 16 + b;
    int c0 = g ^ (key & 7);
    int c1 = (g + 4) ^ (key & 7);
    f32x4 a = (f32x4){0.f, 0.f, 0.f, 0.f};
    a = MFMA16(qf0, *(const bf16x8*)(lk + key * 128 + c0 * 16), a, 0, 0, 0);
    a = MFMA16(qf1, *(const bf16x8*)(lk + key * 128 + c1 * 16), a, 0, 0, 0);
    acc_s[cf] = a;
  }
  // pack T pairs (lo = acc_t[c], hi = acc_t[c+1]) as bf16x2 -> one shuffle
  unsigned pr[4][4];
#pragma unroll
  for (int c = 0; c < 4; ++c)
#pragma unroll
    for (int r = 0; r < 4; ++r)
      pr[c][r] = pack2bf(acc_t[c][r], acc_t[c + 1][r]);

#pragma unroll
  for (int r = 0; r < 4; ++r) {
    const int qw  = 4 * g + r;
    const int sl  = (lane & 48) | ((63 + qw - b) & 15);
    const bool hi = qw > b;
#pragma unroll
    for (int cf = 0; cf < 4; ++cf) {
      unsigned u = __shfl(pr[3 - cf][r], sl);
      float t = hi ? __uint_as_float(u & 0xffff0000u)
                   : __uint_as_float(u << 16);
      float vv = (acc_s[cf][r] + t) * 0.125f;
      if (j0 + cf * 16 + b > i0 + wvx * 16 + qw) vv = MASKV;
      acc_s[cf][r] = vv;
    }
  }
}

// ---------------------------------------------------------------------------
// PRODUCE (single logits pass): grid 4096 = 8 xcd * 2 bh * 256 u.
// u -> qt = 31-(u>>3) (heavy chunks dispatch FIRST), f = u&7.
// K/V/E all LDS-staged (dbuf, counted-vmcnt): the loop body has ZERO global
// loads -- the E gathers (10 x 64-cache-line scatters per wave-step) are
// replaced by coalesced staging + conflict-free ds_read_b128.
// ---------------------------------------------------------------------------
__global__ __launch_bounds__(256, 2)
void produce(const bf16* __restrict__ qh, const bf16* __restrict__ kh,
             const bf16* __restrict__ vt, const bf16* __restrict__ Ebf,
             bf16* __restrict__ P_scr, float* __restrict__ O_slots,
             float* __restrict__ s_buf, float* __restrict__ attn_out)
{
  __shared__ __align__(16) char lds_k[2][64 * 128];   // 16 KB
  __shared__ __align__(16) char lds_v[2][64 * 128];   // 16 KB
  __shared__ __align__(16) char lds_e[2][128 * 128];  // 32 KB
  __shared__ __align__(16) char lds_p[4][16 * 64 * 2];// 8 KB

  const int tid = threadIdx.x, lane = tid & 63, wvx = tid >> 6;
  const int n    = blockIdx.x;
  const int xcd  = n & 7;
  const int r0   = n >> 3;               // 0..511
  const int bh   = 2 * xcd + (r0 & 1);
  const int u    = r0 >> 1;              // 0..255
  const int f    = u & 7;                // chunk index 0..7
  const int qt   = 31 - (u >> 3);        // heavy qt first in dispatch order
  const int nc   = (qt >> 2) + 1;        // # compute chunks for this qt
  if (f >= nc) return;                   // non-compute slot
  const int i0   = qt * 64;
  const int jbeg = f * 4;
  const int jend = (jbeg + 4 < qt + 1) ? jbeg + 4 : qt + 1;

  const bf16* qb = qh + (size_t)bh * Lq * 64;
  const bf16* kb = kh + (size_t)bh * Lq * 64;
  const bf16* vb = vt + (size_t)bh * 64 * Lq;
  float* attn_b = attn_out + (size_t)bh * Lq * Lq;
  bf16* P_b = P_scr + (size_t)bh * Lq * Lq;
  bf16* pst = (bf16*)lds_p[wvx];

  const int qrow = i0 + wvx * 16 + (lane & 15);
  const bf16x8 qf0 = *(const bf16x8*)(qb + (size_t)qrow * 64 + (lane >> 4) * 8);
  const bf16x8 qf1 = *(const bf16x8*)(qb + (size_t)qrow * 64 + 32 + (lane >> 4) * 8);

  f32x4 acc_s[4];
  f32x4 acc_o[4];
  float s_acc[4] = {0.f, 0.f, 0.f, 0.f};
#pragma unroll
  for (int nn = 0; nn < 4; ++nn) acc_o[nn] = (f32x4){0.f, 0.f, 0.f, 0.f};

  // prologue: stage first tile (K+V+E), full drain once
  stage_k(kb, jbeg * BKt, lds_k[0], tid);
  stage_v(vb, jbeg * BKt, lds_v[0], tid);
  stage_e(Ebf, 2110 - i0 + jbeg * BKt, lds_e[0], tid);
  asm volatile("s_waitcnt vmcnt(0)" ::: "memory");
  __builtin_amdgcn_s_barrier();

  int lt = 0;
  for (int jt = jbeg; jt < jend; ++jt) {
    const int j0 = jt * BKt;
    const bool pre = (jt + 1 < jend);
    // issue next-tile staging first (loop body has no other global loads)
    if (pre) {
      stage_k(kb, j0 + BKt, lds_k[lt ^ 1], tid);
      stage_v(vb, j0 + BKt, lds_v[lt ^ 1], tid);
      stage_e(Ebf, 2110 - i0 + j0 + BKt, lds_e[lt ^ 1], tid);
    }
    attn_logits_sh(i0, j0, wvx, lane, qf0, qf1, lds_e[lt], lds_k[lt], acc_s);
    // unnormalized exp -> sum + swizzled P strip (bf16)
#pragma unroll
    for (int cf = 0; cf < 4; ++cf) {
      int kl = cf * 16 + (lane & 15);
      int chs = kl >> 3;
#pragma unroll
      for (int r = 0; r < 4; ++r) {
        int qw = 4 * (lane >> 4) + r;
        float p = __expf(acc_s[cf][r]);
        s_acc[r] += p;
        pst[qw * 64 + ((chs ^ (qw & 7)) * 8) + (kl & 7)] = (bf16)p;
      }
    }
    asm volatile("s_waitcnt lgkmcnt(0)" ::: "memory");
    __builtin_amdgcn_sched_barrier(0);
    // P scratch write (bf16): 128B-contiguous per 8-lane group
#pragma unroll
    for (int it = 0; it < 2; ++it) {
      int qw = it * 8 + (lane >> 3);
      int c = lane & 7;
      bf16x8 pv = *(const bf16x8*)(pst + qw * 64 + ((c ^ (qw & 7)) * 8));
      *(bf16x8*)(P_b + (size_t)(i0 + wvx * 16 + qw) * Lq + j0 + c * 8) = pv;
    }
    // O += P.V (unnormalized)
    __builtin_amdgcn_s_setprio(1);
#pragma unroll
    for (int kc = 0; kc < 2; ++kc) {
      int qa = lane & 15;
      int cha = (kc * 4 + (lane >> 4)) ^ (qa & 7);
      bf16x8 pf = *(const bf16x8*)(pst + qa * 64 + cha * 8);
#pragma unroll
      for (int nn = 0; nn < 4; ++nn) {
        int dh = nn * 16 + (lane & 15);
        int chv = (kc * 4 + (lane >> 4)) ^ (dh & 7);
        bf16x8 vf = *(const bf16x8*)(lds_v[lt] + dh * 128 + chv * 16);
        acc_o[nn] = MFMA16(pf, vf, acc_o[nn], 0, 0, 0);
      }
    }
    __builtin_amdgcn_s_setprio(0);
    if (pre) {
      // counted wait: 8 stage loads must land (2 newest P-stores may linger)
      asm volatile("s_waitcnt vmcnt(2)" ::: "memory");
      __builtin_amdgcn_s_barrier();
      lt ^= 1;
    }
  }

  // O partial -> slot (fp32, unnormalized)
  float* oslot = O_slots + (size_t)(((bh * 32 + qt) * 8 + f)) * 4096;
#pragma unroll
  for (int nn = 0; nn < 4; ++nn)
#pragma unroll
    for (int r = 0; r < 4; ++r) {
      int row = wvx * 16 + 4 * (lane >> 4) + r;
      oslot[row * 64 + nn * 16 + (lane & 15)] = acc_o[nn][r];
    }

  // row-sum atomics
#pragma unroll
  for (int r = 0; r < 4; ++r) {
    float s = s_acc[r];
    for (int d = 1; d < 16; d <<= 1) s += __shfl_xor(s, d);
    if ((lane & 15) == 0)
      atomicAdd(&s_buf[bh * Lq + i0 + wvx * 16 + 4 * (lane >> 4) + r], s);
  }

  // zero-fill this chunk's share of the masked upper tiles (fire-and-forget)
  for (int jz = qt + 1 + f; jz < 32; jz += nc) {
    const int j0 = jz * BKt;
#pragma unroll
    for (int kk = 0; kk < 4; ++kk) {
      int idx = kk * 256 + tid;          // 0..1023 float4 slots in 64x64 tile
      int row = idx >> 4, c4 = idx & 15;
      float* p = attn_b + (size_t)(i0 + row) * Lq + j0 + c4 * 4;
      *(float4*)p = make_float4(0.f, 0.f, 0.f, 0.f);
    }
  }
}

// ---------------------------------------------------------------------------
// FINISH: streaming normalize, fully coalesced. One wave per row (4/block).
// Covers only cols [0, (i&~63)+64) -- masked tiles already zeroed by produce;
// in-tile masked entries are exact 0 in P so no per-element masking needed.
// ---------------------------------------------------------------------------
__global__ __launch_bounds__(256, 8)
void finish(const bf16* __restrict__ P_scr, const float* __restrict__ s_buf,
            float* __restrict__ attn_out)
{
  const int lane = threadIdx.x & 63, wvx = threadIdx.x >> 6;
  const int row = blockIdx.x * 4 + wvx;          // 0..32767 = bh*2048 + i
  const int i   = row & 2047;
  const int ncols = (i & ~63) + 64;
  const float inv = 1.f / s_buf[row];
  const bf16* src = P_scr + (size_t)row * Lq;
  float* dst = attn_out + (size_t)row * Lq;
  for (int c = lane * 4; c < ncols; c += 256) {
    bf16x4 pv = *(const bf16x4*)(src + c);
    float4 fo;
    fo.x = (float)pv[0] * inv;
    fo.y = (float)pv[1] * inv;
    fo.z = (float)pv[2] * inv;
    fo.w = (float)pv[3] * inv;
    *(float4*)(dst + c) = fo;
  }
}

// ---------------------------------------------------------------------------
// Combine O slots -> oh (bf16), scaling by inv_s. Grid 512 = [bh][qt].
// ---------------------------------------------------------------------------
__global__ void combine_o(const float* __restrict__ O_slots,
                          const float* __restrict__ s_buf, bf16* __restrict__ oh)
{
  const int sid = blockIdx.x;            // 0..511
  const int bh = sid >> 5, qt = sid & 31;
  const int nch = (qt >> 2) + 1;
  const float* base = O_slots + (size_t)(bh * 32 + qt) * 8 * 4096;
  const int b = bh >> 3, h = bh & 7;
  for (int e4 = threadIdx.x; e4 < 1024; e4 += 256) {
    float4 s = make_float4(0.f, 0.f, 0.f, 0.f);
    for (int ff = 0; ff < nch; ++ff) {
      float4 x = *(const float4*)(base + ff * 4096 + e4 * 4);
      s.x += x.x; s.y += x.y; s.z += x.z; s.w += x.w;
    }
    int row = e4 >> 4;                   // 0..63 within strip
    int col = (e4 & 15) * 4;
    int ig = qt * 64 + row;
    float inv = 1.f / s_buf[bh * Lq + ig];
    bf16x4 o;
    o[0] = (bf16)(s.x * inv); o[1] = (bf16)(s.y * inv);
    o[2] = (bf16)(s.z * inv); o[3] = (bf16)(s.w * inv);
    *(bf16x4*)(oh + (size_t)(b * 2048 + ig) * 512 + h * 64 + col) = o;
  }
}

// ---------------------------------------------------------------------------
extern "C" void kernel_launch(void* const* d_in, const int* in_sizes, int n_in,
                              void* d_out, int out_size, void* d_ws, size_t ws_size,
                              hipStream_t stream) {
  const float* q    = (const float*)d_in[0];
  const float* k    = (const float*)d_in[1];
  const float* v    = (const float*)d_in[2];
  const float* wq   = (const float*)d_in[3];
  const float* wq_b = (const float*)d_in[4];
  const float* wk   = (const float*)d_in[5];
  const float* wk_b = (const float*)d_in[6];
  const float* wv   = (const float*)d_in[7];
  const float* wv_b = (const float*)d_in[8];
  const float* fc   = (const float*)d_in[9];
  const float* fc_b = (const float*)d_in[10];
  const float* E    = (const float*)d_in[11];

  if (ws_size < 233177088) return;  // layout below (~222 MiB); observed ws ~1.1 GB
  char* ws = (char*)d_ws;
  bf16*  q_bf    = (bf16*)(ws);
  bf16*  k_bf    = (bf16*)(ws + 4194304);
  bf16*  v_bf    = (bf16*)(ws + 8388608);
  bf16*  wq_bf   = (bf16*)(ws + 12582912);
  bf16*  wk_bf   = (bf16*)(ws + 13107200);
  bf16*  wv_bf   = (bf16*)(ws + 13631488);
  bf16*  fc_bf   = (bf16*)(ws + 14155776);
  bf16*  E_bf    = (bf16*)(ws + 14680064);
  float* s_buf   = (float*)(ws + 14942208);
  bf16*  qh_bf   = (bf16*)(ws + 15073280);
  bf16*  kh_bf   = (bf16*)(ws + 19267584);
  bf16*  vt_bf   = (bf16*)(ws + 23461888);
  bf16*  oh_bf   = (bf16*)(ws + 27656192);
  float* O_slots = (float*)(ws + 31850496);   // 64 MiB
  bf16*  P_scr   = (bf16*)(ws + 98959360);    // 128 MiB

  float* out_f  = (float*)d_out;
  float* attn_f = out_f + 2097152;

  convert_all<<<7328, 256, 0, stream>>>(q, k, v, wq, wk, wv, fc, E,
      q_bf, k_bf, v_bf, wq_bf, wk_bf, wv_bf, fc_bf, E_bf, s_buf);
  gemm_qkv<<<dim3(32, 4, 3), 256, 0, stream>>>(q_bf, k_bf, v_bf,
      wq_bf, wk_bf, wv_bf, wq_b, wk_b, wv_b, qh_bf, kh_bf, vt_bf);
  produce<<<4096, 256, 0, stream>>>(qh_bf, kh_bf, vt_bf, E_bf,
                                    P_scr, O_slots, s_buf, attn_f);
  finish<<<8192, 256, 0, stream>>>(P_scr, s_buf, attn_f);
  combine_o<<<512, 256, 0, stream>>>(O_slots, s_buf, oh_bf);
  gemm_fc<<<dim3(32, 4), 256, 0, stream>>>(oh_bf, fc_bf, fc_b, out_f);
}